// Round 1
// baseline (1307.560 us; speedup 1.0000x reference)
//
#include <hip/hip_runtime.h>

// Bidirectional Mamba block, MI355X fp32 baseline.
// B=2, L=2048, d_model=512, d_inner=1024, d_state=16, d_conv=4, dt_rank=32.
//
// Workspace layout (requires ~206 MB):
//   xz    : (2, 4096, 2048) f32  64 MB   in-proj output, t contiguous
//   xconv : (8, 1024, 2048) f32  64 MB   conv+silu output per (combo,b); scan
//                                        overwrites it in place with gated y
//   xdbl  : (8,   64, 2048) f32   4 MB   [dt_r(32); B(16); C(16)] rows
//   delta : (8, 1024, 2048) f32  64 MB   softplus(dt)
//
// combos: 0=(blk0,fwd) t asc | 1=(blk1,fwd) t desc | 2=(blk0,bwd) t desc | 3=(blk1,bwd) t asc
// final out_comb[b,c,t]: c<1024: yg[0][b][c][t]+yg[2][b][c][L-1-t]
//                        c>=1024: yg[3][b][c-1024][t]+yg[1][b][c-1024][L-1-t]

#define SEQ    2048
#define DMODEL 512
#define DINNER 1024
#define NSTATE 16
#define DTRANK 32

__device__ __forceinline__ float siluf(float x)     { return x / (1.f + __expf(-x)); }
__device__ __forceinline__ float softplusf(float x) { return x > 30.f ? x : log1pf(__expf(x)); }

// ---------- K1: xz[b][e][t] = sum_k w_in[e][k] * hs[b][t][k]  (NT sgemm) ----------
__global__ __launch_bounds__(256) void k_gemm_nt(
    const float* __restrict__ A, const float* __restrict__ Bg, float* __restrict__ Cg,
    int M, int N, int K, long sBb, long sCb)
{
  __shared__ float As[16][132];
  __shared__ float Bs[16][132];
  const float* B = Bg + (long)blockIdx.z * sBb;
  float* C = Cg + (long)blockIdx.z * sCb;
  const int m0 = blockIdx.y * 128, n0 = blockIdx.x * 128;
  const int tid = threadIdx.x;
  const int tn = tid & 15, tm = tid >> 4;
  const int lr = tid >> 1, lk = (tid & 1) * 8;
  float acc[8][8];
#pragma unroll
  for (int i = 0; i < 8; ++i)
#pragma unroll
    for (int j = 0; j < 8; ++j) acc[i][j] = 0.f;

  for (int k0 = 0; k0 < K; k0 += 16) {
    const float* ap = A + (long)(m0 + lr) * K + k0 + lk;
    const float* bp = B + (long)(n0 + lr) * K + k0 + lk;
    float4 a0 = *(const float4*)ap;
    float4 a1 = *(const float4*)(ap + 4);
    float4 b0 = *(const float4*)bp;
    float4 b1 = *(const float4*)(bp + 4);
    __syncthreads();
    As[lk+0][lr]=a0.x; As[lk+1][lr]=a0.y; As[lk+2][lr]=a0.z; As[lk+3][lr]=a0.w;
    As[lk+4][lr]=a1.x; As[lk+5][lr]=a1.y; As[lk+6][lr]=a1.z; As[lk+7][lr]=a1.w;
    Bs[lk+0][lr]=b0.x; Bs[lk+1][lr]=b0.y; Bs[lk+2][lr]=b0.z; Bs[lk+3][lr]=b0.w;
    Bs[lk+4][lr]=b1.x; Bs[lk+5][lr]=b1.y; Bs[lk+6][lr]=b1.z; Bs[lk+7][lr]=b1.w;
    __syncthreads();
#pragma unroll
    for (int kk = 0; kk < 16; ++kk) {
      float av[8], bv[8];
      *(float4*)&av[0] = *(const float4*)&As[kk][tm*8];
      *(float4*)&av[4] = *(const float4*)&As[kk][tm*8+4];
      *(float4*)&bv[0] = *(const float4*)&Bs[kk][tn*8];
      *(float4*)&bv[4] = *(const float4*)&Bs[kk][tn*8+4];
#pragma unroll
      for (int i = 0; i < 8; ++i)
#pragma unroll
        for (int j = 0; j < 8; ++j) acc[i][j] = fmaf(av[i], bv[j], acc[i][j]);
    }
  }
#pragma unroll
  for (int i = 0; i < 8; ++i) {
    float* cp = C + (long)(m0 + tm*8 + i) * N + n0 + tn*8;
    float4 v0 = {acc[i][0], acc[i][1], acc[i][2], acc[i][3]};
    float4 v1 = {acc[i][4], acc[i][5], acc[i][6], acc[i][7]};
    *(float4*)cp = v0;
    *(float4*)(cp + 4) = v1;
  }
}

// ---------- K2a: depthwise causal conv + silu, per (combo,b,d) row ----------
__global__ __launch_bounds__(256) void k_conv(
    const float* __restrict__ xz,
    const float* __restrict__ cwf, const float* __restrict__ cbf,
    const float* __restrict__ cwb, const float* __restrict__ cbb,
    float* __restrict__ xconv)
{
  const int d = blockIdx.x;
  const int b = blockIdx.y;
  const int combo = blockIdx.z;
  const int blk = combo & 1, dir = combo >> 1;
  const bool asc = (blk == dir);
  const float* cw = dir ? cwb : cwf;
  const float* cb = dir ? cbb : cbf;
  const float w0 = cw[d*4+0], w1 = cw[d*4+1], w2 = cw[d*4+2], w3 = cw[d*4+3];
  const float bias = cb[d];
  const float* xrow = xz + ((long)b*4096 + blk*2048 + d) * SEQ;
  float* orow = xconv + (((long)combo*2 + b)*DINNER + d) * SEQ;
  const int s0 = threadIdx.x * 8;

  float xv[11];
#pragma unroll
  for (int j = 0; j < 11; ++j) {
    int s = s0 - 3 + j;
    float v = 0.f;
    if (s >= 0) {
      int t = asc ? s : (SEQ - 1 - s);
      v = xrow[t];
    }
    xv[j] = v;
  }
  float ov[8];
#pragma unroll
  for (int j = 0; j < 8; ++j) {
    float y = fmaf(w3, xv[j+3], fmaf(w2, xv[j+2], fmaf(w1, xv[j+1], fmaf(w0, xv[j], bias))));
    ov[j] = siluf(y);
  }
  float4 v0 = {ov[0], ov[1], ov[2], ov[3]};
  float4 v1 = {ov[4], ov[5], ov[6], ov[7]};
  *(float4*)(orow + s0) = v0;
  *(float4*)(orow + s0 + 4) = v1;
}

// ---------- K2b: xdbl[cb][e][s] = sum_d xw[e][d] * xconv[cb][d][s], e<64 ----------
__global__ __launch_bounds__(256) void k_xproj(
    const float* __restrict__ xconv, const float* __restrict__ xwf,
    const float* __restrict__ xwb, float* __restrict__ xdbl)
{
  __shared__ float Ws[16][68];   // [k][e]
  __shared__ float Xs[16][68];   // [k][s]
  const int cb = blockIdx.y;               // combo*2+b
  const float* xw = (cb >> 2) ? xwb : xwf; // dir = combo>>1 = cb>>2
  const int s0 = blockIdx.x * 64;
  const float* xc = xconv + (long)cb * DINNER * SEQ;
  float* outp = xdbl + (long)cb * 64 * SEQ;
  const int tid = threadIdx.x;
  const int eg = tid >> 4, sg = tid & 15;
  const int er = tid >> 2, kc = (tid & 3) * 4;
  const int kr = tid >> 4, sc = (tid & 15) * 4;
  float acc[4][4];
#pragma unroll
  for (int i = 0; i < 4; ++i)
#pragma unroll
    for (int j = 0; j < 4; ++j) acc[i][j] = 0.f;

  for (int k0 = 0; k0 < DINNER; k0 += 16) {
    float4 w = *(const float4*)(xw + (long)er * DINNER + k0 + kc);
    float4 x = *(const float4*)(xc + (long)(k0 + kr) * SEQ + s0 + sc);
    __syncthreads();
    Ws[kc+0][er] = w.x; Ws[kc+1][er] = w.y; Ws[kc+2][er] = w.z; Ws[kc+3][er] = w.w;
    *(float4*)&Xs[kr][sc] = x;
    __syncthreads();
#pragma unroll
    for (int kk = 0; kk < 16; ++kk) {
      float wv[4], xv[4];
      *(float4*)wv = *(const float4*)&Ws[kk][eg*4];
      *(float4*)xv = *(const float4*)&Xs[kk][sg*4];
#pragma unroll
      for (int i = 0; i < 4; ++i)
#pragma unroll
        for (int j = 0; j < 4; ++j) acc[i][j] = fmaf(wv[i], xv[j], acc[i][j]);
    }
  }
#pragma unroll
  for (int i = 0; i < 4; ++i) {
    float4 v = {acc[i][0], acc[i][1], acc[i][2], acc[i][3]};
    *(float4*)(outp + (long)(eg*4 + i) * SEQ + s0 + sg*4) = v;
  }
}

// ---------- K2c: delta[cb][d][s] = softplus(sum_r dw[d][r]*xdbl[cb][r][s] + db[d]) ----------
__global__ __launch_bounds__(256) void k_dtproj(
    const float* __restrict__ xdbl, const float* __restrict__ dwf, const float* __restrict__ dbf,
    const float* __restrict__ dwb, const float* __restrict__ dbb, float* __restrict__ delta)
{
  __shared__ float Wd[32][132];  // [k][d]
  __shared__ float Xr[32][68];   // [k][s]
  const int cb = blockIdx.z;
  const int dir = cb >> 2;
  const float* dw = dir ? dwb : dwf;
  const float* db = dir ? dbb : dbf;
  const int s0 = blockIdx.x * 64, d0 = blockIdx.y * 128;
  const float* xd = xdbl + (long)cb * 64 * SEQ;
  const int tid = threadIdx.x;
  {
    const int dr = tid >> 1, kc2 = (tid & 1) * 16;
    const float* wp = dw + (long)(d0 + dr) * DTRANK + kc2;
    float4 w0 = *(const float4*)(wp);
    float4 w1 = *(const float4*)(wp + 4);
    float4 w2 = *(const float4*)(wp + 8);
    float4 w3 = *(const float4*)(wp + 12);
    const int kr = tid >> 3, sc = (tid & 7) * 8;
    const float* xp = xd + (long)kr * SEQ + s0 + sc;
    float4 x0 = *(const float4*)xp;
    float4 x1 = *(const float4*)(xp + 4);
    Wd[kc2+ 0][dr]=w0.x; Wd[kc2+ 1][dr]=w0.y; Wd[kc2+ 2][dr]=w0.z; Wd[kc2+ 3][dr]=w0.w;
    Wd[kc2+ 4][dr]=w1.x; Wd[kc2+ 5][dr]=w1.y; Wd[kc2+ 6][dr]=w1.z; Wd[kc2+ 7][dr]=w1.w;
    Wd[kc2+ 8][dr]=w2.x; Wd[kc2+ 9][dr]=w2.y; Wd[kc2+10][dr]=w2.z; Wd[kc2+11][dr]=w2.w;
    Wd[kc2+12][dr]=w3.x; Wd[kc2+13][dr]=w3.y; Wd[kc2+14][dr]=w3.z; Wd[kc2+15][dr]=w3.w;
    *(float4*)&Xr[kr][sc] = x0;
    *(float4*)&Xr[kr][sc+4] = x1;
  }
  __syncthreads();
  const int dg = tid >> 4, sg = tid & 15;
  float acc[8][4];
#pragma unroll
  for (int i = 0; i < 8; ++i)
#pragma unroll
    for (int j = 0; j < 4; ++j) acc[i][j] = 0.f;
#pragma unroll
  for (int kk = 0; kk < 32; ++kk) {
    float xv[4], wv[8];
    *(float4*)xv = *(const float4*)&Xr[kk][sg*4];
    *(float4*)&wv[0] = *(const float4*)&Wd[kk][dg*8];
    *(float4*)&wv[4] = *(const float4*)&Wd[kk][dg*8+4];
#pragma unroll
    for (int i = 0; i < 8; ++i)
#pragma unroll
      for (int j = 0; j < 4; ++j) acc[i][j] = fmaf(wv[i], xv[j], acc[i][j]);
  }
#pragma unroll
  for (int i = 0; i < 8; ++i) {
    const int d = d0 + dg*8 + i;
    const float bias = db[d];
    float4 v = { softplusf(acc[i][0] + bias), softplusf(acc[i][1] + bias),
                 softplusf(acc[i][2] + bias), softplusf(acc[i][3] + bias) };
    *(float4*)(delta + ((long)cb * DINNER + d) * SEQ + s0 + sg*4) = v;
  }
}

// ---------- K3: selective scan; writes gated y in place over xconv ----------
__global__ __launch_bounds__(256) void k_scan(
    const float* __restrict__ delta, float* __restrict__ xconv,
    const float* __restrict__ xdbl, const float* __restrict__ xz,
    const float* __restrict__ A_log, const float* __restrict__ A_b_log,
    const float* __restrict__ Df, const float* __restrict__ Db)
{
  const int combo = blockIdx.z, b = blockIdx.y;
  const int tid = threadIdx.x;
  const int n = tid & 15, dl = tid >> 4;
  const int d = blockIdx.x * 16 + dl;
  const int blk = combo & 1, dir = combo >> 1;
  const bool asc = (blk == dir);
  const int cb = combo * 2 + b;

  float a;
  if (dir == 0) {
    a = -__expf(A_log[d * NSTATE + n]);
    if (d >= 512 && d < 528 && (d - 512) == n) a = 0.f;  // mask_diagonal on A_bp
  } else {
    a = -__expf(A_b_log[d * NSTATE + n]);
  }
  const float Dd = dir ? Db[d] : Df[d];

  const float* dp = delta + ((long)cb * DINNER + d) * SEQ;
  float* xp = xconv + ((long)cb * DINNER + d) * SEQ;      // x in, gated y out (in place)
  const float* Bp = xdbl + ((long)cb * 64 + 32 + n) * SEQ;
  const float* Cp = xdbl + ((long)cb * 64 + 48 + n) * SEQ;
  const float* zp = xz + ((long)b * 4096 + blk * 2048 + DINNER + d) * SEQ;

  float h = 0.f;
  for (int s0 = 0; s0 < SEQ; s0 += 4) {
    float d4[4], x4[4], B4[4], C4[4], z4[4];
    *(float4*)d4 = *(const float4*)(dp + s0);
    *(float4*)x4 = *(const float4*)(xp + s0);
    *(float4*)B4 = *(const float4*)(Bp + s0);
    *(float4*)C4 = *(const float4*)(Cp + s0);
    if (asc) *(float4*)z4 = *(const float4*)(zp + s0);
    else     *(float4*)z4 = *(const float4*)(zp + (SEQ - 4 - s0));  // reversed elems

    float y[4];
#pragma unroll
    for (int j = 0; j < 4; ++j) {
      const float dt = d4[j];
      const float e = __expf(dt * a);
      h = fmaf(h, e, dt * x4[j] * B4[j]);
      float p = h * C4[j];
      p += __shfl_xor(p, 1, 16);
      p += __shfl_xor(p, 2, 16);
      p += __shfl_xor(p, 4, 16);
      p += __shfl_xor(p, 8, 16);
      y[j] = p;
    }
    if (n == 0) {
      float o[4];
#pragma unroll
      for (int j = 0; j < 4; ++j) {
        const float zz = asc ? z4[j] : z4[3 - j];
        o[j] = (y[j] + Dd * x4[j]) * siluf(zz);
      }
      float4 v = {o[0], o[1], o[2], o[3]};
      *(float4*)(xp + s0) = v;
    }
  }
}

// ---------- K4: out[b][t][o] = sum_c w_out[o][c] * ycomb(b,c,t); combine fused ----------
__global__ __launch_bounds__(256) void k_gemm_out(
    const float* __restrict__ yg, const float* __restrict__ Wo, float* __restrict__ outp)
{
  __shared__ float As[16][132];  // [c][t]
  __shared__ float Bs[16][132];  // [c][o]
  const int b = blockIdx.z;
  const int t0 = blockIdx.y * 128, o0 = blockIdx.x * 128;
  const int tid = threadIdx.x;
  const int tn = tid & 15, tm = tid >> 4;
  const int kc = tid >> 4;            // c-row for As staging
  const int tt = (tid & 15) * 8;      // t offset within tile
  const int orow = tid >> 1, ck = (tid & 1) * 8;
  float acc[8][8];
#pragma unroll
  for (int i = 0; i < 8; ++i)
#pragma unroll
    for (int j = 0; j < 8; ++j) acc[i][j] = 0.f;

  for (int c0 = 0; c0 < 2 * DINNER; c0 += 16) {
    const int c = c0 + kc;
    const float* p1;
    const float* p2;
    if (c < DINNER) {
      p1 = yg + ((long)(0 * 2 + b) * DINNER + c) * SEQ;           // combo0 @ t
      p2 = yg + ((long)(2 * 2 + b) * DINNER + c) * SEQ;           // combo2 @ L-1-t
    } else {
      p1 = yg + ((long)(3 * 2 + b) * DINNER + (c - DINNER)) * SEQ; // combo3 @ t
      p2 = yg + ((long)(1 * 2 + b) * DINNER + (c - DINNER)) * SEQ; // combo1 @ L-1-t
    }
    const int t = t0 + tt;
    float4 u0 = *(const float4*)(p1 + t);
    float4 u1 = *(const float4*)(p1 + t + 4);
    float4 r0 = *(const float4*)(p2 + (SEQ - 8 - t));
    float4 r1 = *(const float4*)(p2 + (SEQ - 4 - t));
    const float* wp = Wo + (long)(o0 + orow) * (2 * DINNER) + c0 + ck;
    float4 w0 = *(const float4*)wp;
    float4 w1 = *(const float4*)(wp + 4);
    __syncthreads();
    As[kc][tt+0] = u0.x + r1.w;
    As[kc][tt+1] = u0.y + r1.z;
    As[kc][tt+2] = u0.z + r1.y;
    As[kc][tt+3] = u0.w + r1.x;
    As[kc][tt+4] = u1.x + r0.w;
    As[kc][tt+5] = u1.y + r0.z;
    As[kc][tt+6] = u1.z + r0.y;
    As[kc][tt+7] = u1.w + r0.x;
    Bs[ck+0][orow]=w0.x; Bs[ck+1][orow]=w0.y; Bs[ck+2][orow]=w0.z; Bs[ck+3][orow]=w0.w;
    Bs[ck+4][orow]=w1.x; Bs[ck+5][orow]=w1.y; Bs[ck+6][orow]=w1.z; Bs[ck+7][orow]=w1.w;
    __syncthreads();
#pragma unroll
    for (int kk = 0; kk < 16; ++kk) {
      float av[8], bv[8];
      *(float4*)&av[0] = *(const float4*)&As[kk][tm*8];
      *(float4*)&av[4] = *(const float4*)&As[kk][tm*8+4];
      *(float4*)&bv[0] = *(const float4*)&Bs[kk][tn*8];
      *(float4*)&bv[4] = *(const float4*)&Bs[kk][tn*8+4];
#pragma unroll
      for (int i = 0; i < 8; ++i)
#pragma unroll
        for (int j = 0; j < 8; ++j) acc[i][j] = fmaf(av[i], bv[j], acc[i][j]);
    }
  }
#pragma unroll
  for (int i = 0; i < 8; ++i) {
    float* cp = outp + ((long)b * SEQ + t0 + tm*8 + i) * DMODEL + o0 + tn*8;
    float4 v0 = {acc[i][0], acc[i][1], acc[i][2], acc[i][3]};
    float4 v1 = {acc[i][4], acc[i][5], acc[i][6], acc[i][7]};
    *(float4*)cp = v0;
    *(float4*)(cp + 4) = v1;
  }
}

extern "C" void kernel_launch(void* const* d_in, const int* in_sizes, int n_in,
                              void* d_out, int out_size, void* d_ws, size_t ws_size,
                              hipStream_t stream) {
  const float* hs    = (const float*)d_in[0];
  const float* w_in  = (const float*)d_in[1];
  const float* cwf   = (const float*)d_in[2];
  const float* cbf   = (const float*)d_in[3];
  const float* xwf   = (const float*)d_in[4];
  const float* dwf   = (const float*)d_in[5];
  const float* dbf   = (const float*)d_in[6];
  const float* A_log = (const float*)d_in[7];
  const float* Dfp   = (const float*)d_in[8];
  const float* cwb   = (const float*)d_in[9];
  const float* cbb   = (const float*)d_in[10];
  const float* xwb   = (const float*)d_in[11];
  const float* dwb   = (const float*)d_in[12];
  const float* dbb   = (const float*)d_in[13];
  const float* Ablog = (const float*)d_in[14];
  const float* Dbp   = (const float*)d_in[15];
  const float* w_out = (const float*)d_in[16];
  float* out = (float*)d_out;

  char* ws = (char*)d_ws;
  float* xz    = (float*)(ws);                                   // 64 MB
  float* xconv = (float*)(ws + 67108864L);                       // 64 MB (yg in-place)
  float* xdbl  = (float*)(ws + 2 * 67108864L);                   //  4 MB
  float* delta = (float*)(ws + 2 * 67108864L + 4194304L);        // 64 MB

  // K1: in-projection, xz[b][e][t]
  k_gemm_nt<<<dim3(16, 32, 2), 256, 0, stream>>>(
      w_in, hs, xz, 4096, SEQ, DMODEL, (long)SEQ * DMODEL, (long)4096 * SEQ);

  // K2a: conv + silu for all 4 combos
  k_conv<<<dim3(1024, 2, 4), 256, 0, stream>>>(xz, cwf, cbf, cwb, cbb, xconv);

  // K2b: x_dbl projection (64 rows)
  k_xproj<<<dim3(32, 8), 256, 0, stream>>>(xconv, xwf, xwb, xdbl);

  // K2c: dt projection + softplus
  k_dtproj<<<dim3(32, 8, 8), 256, 0, stream>>>(xdbl, dwf, dbf, dwb, dbb, delta);

  // K3: selective scan (gated y overwrites xconv)
  k_scan<<<dim3(64, 2, 4), 256, 0, stream>>>(delta, xconv, xdbl, xz, A_log, Ablog, Dfp, Dbp);

  // K4: output projection with fused direction/channel combine
  k_gemm_out<<<dim3(4, 16, 2), 256, 0, stream>>>(xconv, w_out, out);
}